// Round 5
// baseline (2993.741 us; speedup 1.0000x reference)
//
#include <hip/hip_runtime.h>

#define N_NODES 100000
#define N_EDGES 1600000
#define DIN 128
#define DOUT 128
#define N_SUP 2
#define E_TOT (N_SUP * N_EDGES)          // 3,200,000

#define BIN_ROWS 128
#define BSHIFT 7
#define NBINS ((N_NODES + BIN_ROWS - 1) / BIN_ROWS)    // 782

#define SC_EPT 16
#define SC_BLOCK 256
#define SC_CHUNK (SC_EPT * SC_BLOCK)                    // 4096
#define NBLK_SC ((E_TOT + SC_CHUNK - 1) / SC_CHUNK)     // 782

#define GEMM_ROWS 128
#define LDK 136      // padded LDS k-stride in bf16 units (odd multiple of 8)

// payload.x layout: col (bits 0-16) | support (bit 17) | row_low (bits 18-24)
#define COL_MASK 0x1FFFFu
#define SUP_BIT  0x20000u

typedef float        f32x2 __attribute__((ext_vector_type(2)));
typedef float        f32x4 __attribute__((ext_vector_type(4)));
typedef unsigned int u32;
typedef u32          u32x2 __attribute__((ext_vector_type(2)));
typedef u32          u32x4 __attribute__((ext_vector_type(4)));
typedef short        bf16x8 __attribute__((ext_vector_type(8)));

// round-to-nearest-even fp32 -> bf16 pair packed in one u32 (lo, hi)
static __device__ __forceinline__ u32 pack_bf16x2(float lo, float hi) {
    u32 ul = __float_as_uint(lo);
    u32 uh = __float_as_uint(hi);
    ul = (ul + 0x7FFFu + ((ul >> 16) & 1u)) >> 16;
    uh = ((uh + 0x7FFFu + ((uh >> 16) & 1u)) >> 16) << 16;
    return ul | uh;
}

// ---------------------------------------------------------------------------
// x -> packed bf16 [node][64 u32]; word j packs features (j, j+64).
// This (f, f+64) pairing makes the bingather's two ds_add_f32 per lane
// conflict-free (lane l -> float idx base+l and base+l+64: same bank, but
// separate instructions, each 2-way across the wave = free).
// The K-axis permutation is applied identically to wTb, so the GEMM dot
// product is unchanged.
// ---------------------------------------------------------------------------
__global__ __launch_bounds__(256) void xconv_kernel(const float* __restrict__ x,
                                                    u32* __restrict__ xb) {
    const int idx = blockIdx.x * 256 + threadIdx.x;   // node*16 + part
    const int total = N_NODES * 16;                   // 1.6M
    if (idx < total) {
        const int node = idx >> 4;
        const int p = idx & 15;                       // words p*4 .. p*4+3
        const float* base = x + (size_t)node * DIN + p * 4;
        const f32x4 a = __builtin_nontemporal_load((const f32x4*)base);
        const f32x4 b = __builtin_nontemporal_load((const f32x4*)(base + 64));
        u32x4 o;
        o.x = pack_bf16x2(a.x, b.x);
        o.y = pack_bf16x2(a.y, b.y);
        o.z = pack_bf16x2(a.z, b.z);
        o.w = pack_bf16x2(a.w, b.w);
        __builtin_nontemporal_store(o, (u32x4*)(xb + (size_t)node * 64 + p * 4));
    }
}

// ---------------------------------------------------------------------------
// w[s][k][n] fp32 -> wTcat[n][128 u32]; word (s*64 + j) packs
// (w[s][j][n], w[s][j+64][n]) -- same K-pair permutation as xb/Y.
// ---------------------------------------------------------------------------
__global__ __launch_bounds__(256) void wconv_kernel(const float* __restrict__ w,
                                                    u32* __restrict__ wTb) {
    const int s = blockIdx.x;
    const int n = threadIdx.x >> 1;
    const int h = threadIdx.x & 1;        // j-half: 0..31 / 32..63
    const float* wp = w + (size_t)s * DIN * DOUT + n;
    u32 o[32];
    #pragma unroll
    for (int jj = 0; jj < 32; jj++) {
        const int j = h * 32 + jj;
        const float lo = wp[(size_t)j * DOUT];
        const float hi = wp[(size_t)(j + 64) * DOUT];
        o[jj] = pack_bf16x2(lo, hi);
    }
    u32* op = wTb + (size_t)n * 128 + s * 64 + h * 32;
    #pragma unroll
    for (int j = 0; j < 8; j++)
        *(u32x4*)(op + j * 4) = *(u32x4*)&o[j * 4];
}

// ---------------------------------------------------------------------------
// Bin histogram: LDS hist per block, one global atomic per (block, bin)
// ---------------------------------------------------------------------------
__global__ __launch_bounds__(256) void binhist_kernel(const int* __restrict__ rows,
                                                      int* __restrict__ bin_cnt) {
    __shared__ int h[NBINS];
    const int t = threadIdx.x;
    for (int i = t; i < NBINS; i += 256) h[i] = 0;
    __syncthreads();
    const int base = blockIdx.x * SC_CHUNK;
    #pragma unroll
    for (int j = 0; j < SC_EPT; j++) {
        const int i = base + j * 256 + t;
        if (i < E_TOT) atomicAdd(&h[__builtin_nontemporal_load(rows + i) >> BSHIFT], 1);
    }
    __syncthreads();
    for (int i = t; i < NBINS; i += 256)
        if (h[i]) atomicAdd(&bin_cnt[i], h[i]);
}

// ---------------------------------------------------------------------------
// Exclusive scan over NBINS (single block)
// ---------------------------------------------------------------------------
__global__ __launch_bounds__(1024) void binscan_kernel(const int* __restrict__ bin_cnt,
                                                       int* __restrict__ bin_base,
                                                       int* __restrict__ bin_cursor) {
    __shared__ int s[1024];
    const int t = threadIdx.x;
    const int v = (t < NBINS) ? bin_cnt[t] : 0;
    s[t] = v;
    __syncthreads();
    #pragma unroll
    for (int off = 1; off < 1024; off <<= 1) {
        const int u = (t >= off) ? s[t - off] : 0;
        __syncthreads();
        s[t] += u;
        __syncthreads();
    }
    if (t < NBINS) {
        const int ex = s[t] - v;
        bin_base[t] = ex;
        bin_cursor[t] = ex;
    }
    if (t == 0) bin_base[NBINS] = E_TOT;
}

// ---------------------------------------------------------------------------
// Binned scatter: per-block LDS bin counts, one global run reservation per
// (block,bin), stores at run_base + local_pos (block-local contiguous runs).
// payload.x = col (17b) | support (1b) << 17 | row_low (7b) << 18
// payload.y = val bits
// ---------------------------------------------------------------------------
__global__ __launch_bounds__(256) void binscatter_kernel(const int* __restrict__ rows,
                                                         const int* __restrict__ cols,
                                                         const float* __restrict__ vals,
                                                         int* __restrict__ bin_cursor,
                                                         u32x2* __restrict__ edata) {
    __shared__ int lcnt[NBINS];
    __shared__ int lbase[NBINS];
    const int t = threadIdx.x;
    for (int i = t; i < NBINS; i += 256) lcnt[i] = 0;
    __syncthreads();

    const int base = blockIdx.x * SC_CHUNK;
    int bin[SC_EPT], lpos[SC_EPT];
    u32x2 pay[SC_EPT];
    #pragma unroll
    for (int j = 0; j < SC_EPT; j++) {
        const int i = base + j * 256 + t;
        if (i < E_TOT) {
            const int r = __builtin_nontemporal_load(rows + i);
            const int c = __builtin_nontemporal_load(cols + i);
            const float v = __builtin_nontemporal_load(vals + i);
            const int b = r >> BSHIFT;
            bin[j] = b;
            lpos[j] = atomicAdd(&lcnt[b], 1);
            pay[j].x = (u32)c | ((i >= N_EDGES) ? SUP_BIT : 0u) |
                       ((u32)(r & (BIN_ROWS - 1)) << 18);
            pay[j].y = __float_as_uint(v);
        } else {
            bin[j] = -1;
        }
    }
    __syncthreads();
    for (int b = t; b < NBINS; b += 256) {
        const int c = lcnt[b];
        if (c) lbase[b] = atomicAdd(&bin_cursor[b], c);
    }
    __syncthreads();
    #pragma unroll
    for (int j = 0; j < SC_EPT; j++) {
        if (bin[j] >= 0) edata[lbase[bin[j]] + lpos[j]] = pay[j];
    }
}

// ---------------------------------------------------------------------------
// Bin gather with LDS accumulation (replaces binsort + row gather):
// one block per 128-row bin; 128x256 fp32 accumulator in LDS (128 KiB).
// Streams the bin's UNSORTED edges; per edge, lane l gathers xb word l
// (features l, l+64 of the col row) and does two native ds_add_f32 into
// accum[(rl*2+sup)*128 + l] and [.. + 64]. No branches, no tails per row,
// no cndmask, no global atomics. Writeback packs Y[node][128 u32] =
// [sup0 pairs (j,j+64) x64 | sup1 pairs x64], matching wTb's K order.
// ---------------------------------------------------------------------------
__global__ __launch_bounds__(1024) void bingather_kernel(const u32* __restrict__ xb,
                                                         const u32x2* __restrict__ edata,
                                                         const int* __restrict__ bin_base,
                                                         u32* __restrict__ Y) {
    __shared__ float accum[BIN_ROWS * 256];   // 131,072 B
    const int t = threadIdx.x;
    const int lane = t & 63;
    const int wid = t >> 6;                   // 0..15
    const int b = blockIdx.x;

    // zero accum: 32768 floats / 1024 threads = 8x f32x4 each
    #pragma unroll
    for (int j = 0; j < 8; j++)
        *(f32x4*)&accum[(j * 1024 + t) * 4] = (f32x4){0.f, 0.f, 0.f, 0.f};
    __syncthreads();

    const int beg = bin_base[b];
    const int end = bin_base[b + 1];
    const int cnt = end - beg;
    const int chunk = (cnt + 15) >> 4;
    int e = beg + wid * chunk;
    const int we = min(e + chunk, end);

    // 8-deep batches: 8 independent 256B gathers in flight per wave
    for (; e + 8 <= we; e += 8) {
        u32x2 d[8];
        #pragma unroll
        for (int j = 0; j < 8; j++)
            d[j] = __builtin_nontemporal_load(edata + e + j);
        u32 u[8];
        #pragma unroll
        for (int j = 0; j < 8; j++)
            u[j] = xb[(u32)(((d[j].x & COL_MASK) << 6) + (u32)lane)];
        #pragma unroll
        for (int j = 0; j < 8; j++) {
            const float v = __uint_as_float(d[j].y);
            const int base = (int)(((d[j].x >> 17) & 255u) << 7) + lane;
            unsafeAtomicAdd(&accum[base],      v * __uint_as_float(u[j] << 16));
            unsafeAtomicAdd(&accum[base + 64], v * __uint_as_float(u[j] & 0xFFFF0000u));
        }
    }
    for (; e < we; e++) {
        const u32x2 d = __builtin_nontemporal_load(edata + e);
        const u32 u = xb[(u32)(((d.x & COL_MASK) << 6) + (u32)lane)];
        const float v = __uint_as_float(d.y);
        const int base = (int)(((d.x >> 17) & 255u) << 7) + lane;
        unsafeAtomicAdd(&accum[base],      v * __uint_as_float(u << 16));
        unsafeAtomicAdd(&accum[base + 64], v * __uint_as_float(u & 0xFFFF0000u));
    }
    __syncthreads();

    // writeback: 128 rows x 128 u32 words = 16384 words / 1024 threads
    const int row0 = b * BIN_ROWS;
    #pragma unroll
    for (int j = 0; j < 16; j++) {
        const int wdx = j * 1024 + t;         // consecutive t -> consecutive words
        const int r = wdx >> 7;
        const int i = wdx & 127;              // i = s*64 + jj
        const int gr = row0 + r;
        if (gr < N_NODES) {
            const int s = i >> 6;
            const int jj = i & 63;
            const float lo = accum[r * 256 + s * 128 + jj];
            const float hi = accum[r * 256 + s * 128 + jj + 64];
            __builtin_nontemporal_store(pack_bf16x2(lo, hi),
                                        Y + (size_t)gr * 128 + i);
        }
    }
}

// ---------------------------------------------------------------------------
// Final MFMA GEMM: out = relu(Ycat @ Wcat + bias), Ycat [N,256] bf16,
// Wcat [256,128] bf16 (stacked [W0;W1]). K=256 via two manually-unrolled
// staged k-halves. Block: 128 rows x 128 cols, 4 waves; wave = 2x8 tiles.
// LDS: stage 69.6 KB (2 blocks/CU); epilogue re-uses as 128x129 fp32.
// K order is the (f, f+64)-pair permutation -- identical on Y and wTb,
// so the contraction is unchanged.
// ---------------------------------------------------------------------------
__global__ __launch_bounds__(256) void mfma_gemm_kernel(const u32* __restrict__ Y,
                                                        const u32* __restrict__ wTb,
                                                        const float* __restrict__ bias,
                                                        float* __restrict__ out) {
    __shared__ alignas(16) unsigned short stage[2][GEMM_ROWS][LDK];  // 69,632 B
    float (*epi)[129] = (float (*)[129])(void*)stage;                // 66,048 B

    const int row0 = blockIdx.x * GEMM_ROWS;
    const int t = threadIdx.x;
    const int lane = t & 63;
    const int wv = t >> 6;

    const int q = lane >> 4;       // quad: k sub-block
    const int ml = lane & 15;      // row within m-tile / col within n-tile
    const int m0 = wv * 32;

    f32x4 acc[2][8];
    #pragma unroll
    for (int mt = 0; mt < 2; mt++)
        #pragma unroll
        for (int nt = 0; nt < 8; nt++) acc[mt][nt] = (f32x4){0.f, 0.f, 0.f, 0.f};

    const int r = t >> 1;
    const int half = t & 1;               // k-quarter within the k-half
    const int gr = row0 + r;

    // ---- k-half 0 ----
    {
        u32* dst = (u32*)&stage[0][r][half * 64];
        if (gr < N_NODES) {
            const u32* p = Y + (size_t)gr * 128 + half * 32;
            #pragma unroll
            for (int j = 0; j < 8; j++)
                *(u32x4*)(dst + j * 4) = *(const u32x4*)(p + j * 4);
        } else {
            #pragma unroll
            for (int j = 0; j < 8; j++)
                *(u32x4*)(dst + j * 4) = (u32x4){0, 0, 0, 0};
        }
        const u32* wp = wTb + (size_t)r * 128 + half * 32;
        u32* wdst = (u32*)&stage[1][r][half * 64];
        #pragma unroll
        for (int j = 0; j < 8; j++)
            *(u32x4*)(wdst + j * 4) = *(const u32x4*)(wp + j * 4);
    }
    __syncthreads();
    #pragma unroll
    for (int kt = 0; kt < 4; kt++) {
        const int k0 = kt * 32 + q * 8;
        const bf16x8 a0 = *(const bf16x8*)&stage[0][m0 + ml][k0];
        const bf16x8 a1 = *(const bf16x8*)&stage[0][m0 + 16 + ml][k0];
        #pragma unroll
        for (int nt = 0; nt < 8; nt++) {
            const bf16x8 b = *(const bf16x8*)&stage[1][nt * 16 + ml][k0];
            acc[0][nt] = __builtin_amdgcn_mfma_f32_16x16x32_bf16(a0, b, acc[0][nt], 0, 0, 0);
            acc[1][nt] = __builtin_amdgcn_mfma_f32_16x16x32_bf16(a1, b, acc[1][nt], 0, 0, 0);
        }
    }
    __syncthreads();

    // ---- k-half 1 ----
    {
        u32* dst = (u32*)&stage[0][r][half * 64];
        if (gr < N_NODES) {
            const u32* p = Y + (size_t)gr * 128 + 64 + half * 32;
            #pragma unroll
            for (int j = 0; j < 8; j++)
                *(u32x4*)(dst + j * 4) = *(const u32x4*)(p + j * 4);
        } else {
            #pragma unroll
            for (int j = 0; j < 8; j++)
                *(u32x4*)(dst + j * 4) = (u32x4){0, 0, 0, 0};
        }
        const u32* wp = wTb + (size_t)r * 128 + 64 + half * 32;
        u32* wdst = (u32*)&stage[1][r][half * 64];
        #pragma unroll
        for (int j = 0; j < 8; j++)
            *(u32x4*)(wdst + j * 4) = *(const u32x4*)(wp + j * 4);
    }
    __syncthreads();
    #pragma unroll
    for (int kt = 0; kt < 4; kt++) {
        const int k0 = kt * 32 + q * 8;
        const bf16x8 a0 = *(const bf16x8*)&stage[0][m0 + ml][k0];
        const bf16x8 a1 = *(const bf16x8*)&stage[0][m0 + 16 + ml][k0];
        #pragma unroll
        for (int nt = 0; nt < 8; nt++) {
            const bf16x8 b = *(const bf16x8*)&stage[1][nt * 16 + ml][k0];
            acc[0][nt] = __builtin_amdgcn_mfma_f32_16x16x32_bf16(a0, b, acc[0][nt], 0, 0, 0);
            acc[1][nt] = __builtin_amdgcn_mfma_f32_16x16x32_bf16(a1, b, acc[1][nt], 0, 0, 0);
        }
    }
    __syncthreads();   // done reading stage; epi aliases it

    // C-layout (col=lane&15, row=quad*4+reg) -> LDS fp32 [row][feat]
    #pragma unroll
    for (int mt = 0; mt < 2; mt++)
        #pragma unroll
        for (int nt = 0; nt < 8; nt++)
            #pragma unroll
            for (int rr = 0; rr < 4; rr++)
                epi[m0 + mt * 16 + q * 4 + rr][nt * 16 + ml] = acc[mt][nt][rr];
    __syncthreads();

    // fused bias + relu, coalesced fp32 store
    if (gr < N_NODES) {
        float* op = out + (size_t)gr * DOUT + half * 64;
        const float* bp = bias + half * 64;
        #pragma unroll
        for (int j = 0; j < 16; j++) {
            const f32x4 bv = *(const f32x4*)(bp + j * 4);
            f32x4 v = *(const f32x4*)&epi[r][half * 64 + j * 4];
            v.x = fmaxf(v.x + bv.x, 0.f);
            v.y = fmaxf(v.y + bv.y, 0.f);
            v.z = fmaxf(v.z + bv.z, 0.f);
            v.w = fmaxf(v.w + bv.w, 0.f);
            __builtin_nontemporal_store(v, (f32x4*)(op + j * 4));
        }
    }
}

extern "C" void kernel_launch(void* const* d_in, const int* in_sizes, int n_in,
                              void* d_out, int out_size, void* d_ws, size_t ws_size,
                              hipStream_t stream) {
    (void)in_sizes; (void)n_in; (void)out_size; (void)ws_size;
    const float* x        = (const float*)d_in[0];   // [N, 128]
    const float* w        = (const float*)d_in[1];   // [2, 128, 128]
    const float* bias     = (const float*)d_in[2];   // [128]
    const float* sup_vals = (const float*)d_in[3];   // [2, E] flat
    const int*   sup_rows = (const int*)d_in[4];     // [2, E] flat
    const int*   sup_cols = (const int*)d_in[5];     // [2, E] flat
    float* out = (float*)d_out;                      // [N, 128]

    // ws layout: xb | edata | Y | bins | wTb  (~102.5 MB; edata and Y are
    // simultaneously live in bingather -> no aliasing)
    char* ws = (char*)d_ws;
    u32*   xb     = (u32*)ws;                                   // 25.6 MB
    u32x2* edata  = (u32x2*)(ws + (size_t)N_NODES * 64 * 4);    // 25.6 MB
    u32*   Y      = (u32*)((char*)edata + (size_t)E_TOT * 8);   // 51.2 MB
    int*   bin_cnt   = (int*)((char*)Y + (size_t)N_NODES * 128 * 4);
    int*   bin_base  = bin_cnt + NBINS;              // NBINS+1
    int*   bin_cursor= bin_base + NBINS + 1;
    u32*   wTb       = (u32*)(bin_cursor + NBINS);   // 64 KB

    // 1. convert x -> bf16 table, w -> stacked transposed bf16
    xconv_kernel<<<(N_NODES * 16 + 255) / 256, 256, 0, stream>>>(x, xb);
    wconv_kernel<<<N_SUP, 256, 0, stream>>>(w, wTb);
    // 2. bin CSR build (both supports merged; no row sort needed)
    (void)hipMemsetAsync(bin_cnt, 0, NBINS * sizeof(int), stream);
    binhist_kernel<<<NBLK_SC, 256, 0, stream>>>(sup_rows, bin_cnt);
    binscan_kernel<<<1, 1024, 0, stream>>>(bin_cnt, bin_base, bin_cursor);
    binscatter_kernel<<<NBLK_SC, 256, 0, stream>>>(sup_rows, sup_cols, sup_vals,
                                                   bin_cursor, edata);
    // 3. bin gather with LDS fp32 accumulation -> Y (replaces binsort+gather)
    bingather_kernel<<<NBINS, 1024, 0, stream>>>(xb, edata, bin_base, Y);
    // 4. K=256 MFMA GEMM with fused bias + ReLU
    mfma_gemm_kernel<<<(N_NODES + GEMM_ROWS - 1) / GEMM_ROWS, 256, 0, stream>>>(Y, wTb, bias, out);
}

// Round 6
// 2991.362 us; speedup vs baseline: 1.0008x; 1.0008x over previous
//
#include <hip/hip_runtime.h>

#define N_NODES 100000
#define N_EDGES 1600000
#define DIN 128
#define DOUT 128
#define N_SUP 2
#define E_TOT (N_SUP * N_EDGES)          // 3,200,000

#define BIN_ROWS 128
#define BSHIFT 7
#define NBINS ((N_NODES + BIN_ROWS - 1) / BIN_ROWS)    // 782

#define SC_EPT 16
#define SC_BLOCK 256
#define SC_CHUNK (SC_EPT * SC_BLOCK)                    // 4096
#define NBLK_SC ((E_TOT + SC_CHUNK - 1) / SC_CHUNK)     // 782

#define GEMM_ROWS 128
#define LDK 136      // padded LDS k-stride in bf16 units (odd multiple of 8)

// payload.x layout: col (bits 0-16) | support (bit 17) | row_low (bits 18-24)
#define COL_MASK 0x1FFFFu
#define SUP_BIT  0x20000u

typedef float        f32x2 __attribute__((ext_vector_type(2)));
typedef float        f32x4 __attribute__((ext_vector_type(4)));
typedef unsigned int u32;
typedef u32          u32x2 __attribute__((ext_vector_type(2)));
typedef u32          u32x4 __attribute__((ext_vector_type(4)));
typedef short        bf16x8 __attribute__((ext_vector_type(8)));

// round-to-nearest-even fp32 -> bf16 pair packed in one u32 (lo, hi)
static __device__ __forceinline__ u32 pack_bf16x2(float lo, float hi) {
    u32 ul = __float_as_uint(lo);
    u32 uh = __float_as_uint(hi);
    ul = (ul + 0x7FFFu + ((ul >> 16) & 1u)) >> 16;
    uh = ((uh + 0x7FFFu + ((uh >> 16) & 1u)) >> 16) << 16;
    return ul | uh;
}

// Native LDS fp32 atomic add (ds_add_f32), wave-parallel, no return.
// R5 post-mortem: unsafeAtomicAdd on a __shared__ float goes through the
// generic path -> flat_atomic_add_f32 -> ~per-lane processing (2650us).
// ds_add_f32 is the workgroup-scope LDS atomic (~8 cyc/wave-instr).
// LDS byte address = low 32 bits of the generic pointer (LLVM lowers
// local->generic addrspacecast as {aperture_hi32, lds_offset32}).
static __device__ __forceinline__ void lds_add_f32(float* p, float v) {
    asm volatile("ds_add_f32 %0, %1"
                 :
                 : "v"((u32)(size_t)p), "v"(v)
                 : "memory");
}

// ---------------------------------------------------------------------------
// x -> packed bf16 [node][64 u32]; word j packs features (j, j+64).
// This (f, f+64) pairing makes the bingather's two ds_add_f32 per lane
// conflict-free. The K-axis permutation is applied identically to wTb, so
// the GEMM dot product is unchanged.
// ---------------------------------------------------------------------------
__global__ __launch_bounds__(256) void xconv_kernel(const float* __restrict__ x,
                                                    u32* __restrict__ xb) {
    const int idx = blockIdx.x * 256 + threadIdx.x;   // node*16 + part
    const int total = N_NODES * 16;                   // 1.6M
    if (idx < total) {
        const int node = idx >> 4;
        const int p = idx & 15;                       // words p*4 .. p*4+3
        const float* base = x + (size_t)node * DIN + p * 4;
        const f32x4 a = __builtin_nontemporal_load((const f32x4*)base);
        const f32x4 b = __builtin_nontemporal_load((const f32x4*)(base + 64));
        u32x4 o;
        o.x = pack_bf16x2(a.x, b.x);
        o.y = pack_bf16x2(a.y, b.y);
        o.z = pack_bf16x2(a.z, b.z);
        o.w = pack_bf16x2(a.w, b.w);
        __builtin_nontemporal_store(o, (u32x4*)(xb + (size_t)node * 64 + p * 4));
    }
}

// ---------------------------------------------------------------------------
// w[s][k][n] fp32 -> wTcat[n][128 u32]; word (s*64 + j) packs
// (w[s][j][n], w[s][j+64][n]) -- same K-pair permutation as xb/Y.
// ---------------------------------------------------------------------------
__global__ __launch_bounds__(256) void wconv_kernel(const float* __restrict__ w,
                                                    u32* __restrict__ wTb) {
    const int s = blockIdx.x;
    const int n = threadIdx.x >> 1;
    const int h = threadIdx.x & 1;        // j-half: 0..31 / 32..63
    const float* wp = w + (size_t)s * DIN * DOUT + n;
    u32 o[32];
    #pragma unroll
    for (int jj = 0; jj < 32; jj++) {
        const int j = h * 32 + jj;
        const float lo = wp[(size_t)j * DOUT];
        const float hi = wp[(size_t)(j + 64) * DOUT];
        o[jj] = pack_bf16x2(lo, hi);
    }
    u32* op = wTb + (size_t)n * 128 + s * 64 + h * 32;
    #pragma unroll
    for (int j = 0; j < 8; j++)
        *(u32x4*)(op + j * 4) = *(u32x4*)&o[j * 4];
}

// ---------------------------------------------------------------------------
// Bin histogram: LDS hist per block, one global atomic per (block, bin)
// ---------------------------------------------------------------------------
__global__ __launch_bounds__(256) void binhist_kernel(const int* __restrict__ rows,
                                                      int* __restrict__ bin_cnt) {
    __shared__ int h[NBINS];
    const int t = threadIdx.x;
    for (int i = t; i < NBINS; i += 256) h[i] = 0;
    __syncthreads();
    const int base = blockIdx.x * SC_CHUNK;
    #pragma unroll
    for (int j = 0; j < SC_EPT; j++) {
        const int i = base + j * 256 + t;
        if (i < E_TOT) atomicAdd(&h[__builtin_nontemporal_load(rows + i) >> BSHIFT], 1);
    }
    __syncthreads();
    for (int i = t; i < NBINS; i += 256)
        if (h[i]) atomicAdd(&bin_cnt[i], h[i]);
}

// ---------------------------------------------------------------------------
// Exclusive scan over NBINS (single block)
// ---------------------------------------------------------------------------
__global__ __launch_bounds__(1024) void binscan_kernel(const int* __restrict__ bin_cnt,
                                                       int* __restrict__ bin_base,
                                                       int* __restrict__ bin_cursor) {
    __shared__ int s[1024];
    const int t = threadIdx.x;
    const int v = (t < NBINS) ? bin_cnt[t] : 0;
    s[t] = v;
    __syncthreads();
    #pragma unroll
    for (int off = 1; off < 1024; off <<= 1) {
        const int u = (t >= off) ? s[t - off] : 0;
        __syncthreads();
        s[t] += u;
        __syncthreads();
    }
    if (t < NBINS) {
        const int ex = s[t] - v;
        bin_base[t] = ex;
        bin_cursor[t] = ex;
    }
    if (t == 0) bin_base[NBINS] = E_TOT;
}

// ---------------------------------------------------------------------------
// Binned scatter: per-block LDS bin counts, one global run reservation per
// (block,bin), stores at run_base + local_pos (block-local contiguous runs).
// payload.x = col (17b) | support (1b) << 17 | row_low (7b) << 18
// payload.y = val bits
// ---------------------------------------------------------------------------
__global__ __launch_bounds__(256) void binscatter_kernel(const int* __restrict__ rows,
                                                         const int* __restrict__ cols,
                                                         const float* __restrict__ vals,
                                                         int* __restrict__ bin_cursor,
                                                         u32x2* __restrict__ edata) {
    __shared__ int lcnt[NBINS];
    __shared__ int lbase[NBINS];
    const int t = threadIdx.x;
    for (int i = t; i < NBINS; i += 256) lcnt[i] = 0;
    __syncthreads();

    const int base = blockIdx.x * SC_CHUNK;
    int bin[SC_EPT], lpos[SC_EPT];
    u32x2 pay[SC_EPT];
    #pragma unroll
    for (int j = 0; j < SC_EPT; j++) {
        const int i = base + j * 256 + t;
        if (i < E_TOT) {
            const int r = __builtin_nontemporal_load(rows + i);
            const int c = __builtin_nontemporal_load(cols + i);
            const float v = __builtin_nontemporal_load(vals + i);
            const int b = r >> BSHIFT;
            bin[j] = b;
            lpos[j] = atomicAdd(&lcnt[b], 1);
            pay[j].x = (u32)c | ((i >= N_EDGES) ? SUP_BIT : 0u) |
                       ((u32)(r & (BIN_ROWS - 1)) << 18);
            pay[j].y = __float_as_uint(v);
        } else {
            bin[j] = -1;
        }
    }
    __syncthreads();
    for (int b = t; b < NBINS; b += 256) {
        const int c = lcnt[b];
        if (c) lbase[b] = atomicAdd(&bin_cursor[b], c);
    }
    __syncthreads();
    #pragma unroll
    for (int j = 0; j < SC_EPT; j++) {
        if (bin[j] >= 0) edata[lbase[bin[j]] + lpos[j]] = pay[j];
    }
}

// ---------------------------------------------------------------------------
// Bin gather with LDS accumulation (replaces binsort + row gather):
// one block per 128-row bin; 128x256 fp32 accumulator in LDS (128 KiB).
// Streams the bin's UNSORTED edges; per edge, lane l gathers xb word l
// (features l, l+64 of the col row) and does two native ds_add_f32 into
// accum[(rl*2+sup)*128 + l] and [.. + 64]. No global atomics. Writeback
// packs Y[node][128 u32] = [sup0 pairs (j,j+64) x64 | sup1 pairs x64],
// matching wTb's K order. (Algorithm verified correct in R5; this round
// only swaps the flat atomic for ds_add_f32.)
// ---------------------------------------------------------------------------
__global__ __launch_bounds__(1024) void bingather_kernel(const u32* __restrict__ xb,
                                                         const u32x2* __restrict__ edata,
                                                         const int* __restrict__ bin_base,
                                                         u32* __restrict__ Y) {
    __shared__ float accum[BIN_ROWS * 256];   // 131,072 B
    const int t = threadIdx.x;
    const int lane = t & 63;
    const int wid = t >> 6;                   // 0..15
    const int b = blockIdx.x;

    // zero accum: 32768 floats / 1024 threads = 8x f32x4 each
    #pragma unroll
    for (int j = 0; j < 8; j++)
        *(f32x4*)&accum[(j * 1024 + t) * 4] = (f32x4){0.f, 0.f, 0.f, 0.f};
    __syncthreads();

    const int beg = bin_base[b];
    const int end = bin_base[b + 1];
    const int cnt = end - beg;
    const int chunk = (cnt + 15) >> 4;
    int e = beg + wid * chunk;
    const int we = min(e + chunk, end);

    // 8-deep batches: 8 independent 256B gathers in flight per wave
    for (; e + 8 <= we; e += 8) {
        u32x2 d[8];
        #pragma unroll
        for (int j = 0; j < 8; j++)
            d[j] = __builtin_nontemporal_load(edata + e + j);
        u32 u[8];
        #pragma unroll
        for (int j = 0; j < 8; j++)
            u[j] = xb[(u32)(((d[j].x & COL_MASK) << 6) + (u32)lane)];
        #pragma unroll
        for (int j = 0; j < 8; j++) {
            const float v = __uint_as_float(d[j].y);
            const int base = (int)(((d[j].x >> 17) & 255u) << 7) + lane;
            lds_add_f32(&accum[base],      v * __uint_as_float(u[j] << 16));
            lds_add_f32(&accum[base + 64], v * __uint_as_float(u[j] & 0xFFFF0000u));
        }
    }
    for (; e < we; e++) {
        const u32x2 d = __builtin_nontemporal_load(edata + e);
        const u32 u = xb[(u32)(((d.x & COL_MASK) << 6) + (u32)lane)];
        const float v = __uint_as_float(d.y);
        const int base = (int)(((d.x >> 17) & 255u) << 7) + lane;
        lds_add_f32(&accum[base],      v * __uint_as_float(u << 16));
        lds_add_f32(&accum[base + 64], v * __uint_as_float(u & 0xFFFF0000u));
    }
    __syncthreads();

    // writeback: 128 rows x 128 u32 words = 16384 words / 1024 threads
    const int row0 = b * BIN_ROWS;
    #pragma unroll
    for (int j = 0; j < 16; j++) {
        const int wdx = j * 1024 + t;         // consecutive t -> consecutive words
        const int r = wdx >> 7;
        const int i = wdx & 127;              // i = s*64 + jj
        const int gr = row0 + r;
        if (gr < N_NODES) {
            const int s = i >> 6;
            const int jj = i & 63;
            const float lo = accum[r * 256 + s * 128 + jj];
            const float hi = accum[r * 256 + s * 128 + jj + 64];
            __builtin_nontemporal_store(pack_bf16x2(lo, hi),
                                        Y + (size_t)gr * 128 + i);
        }
    }
}

// ---------------------------------------------------------------------------
// Final MFMA GEMM: out = relu(Ycat @ Wcat + bias), Ycat [N,256] bf16,
// Wcat [256,128] bf16 (stacked [W0;W1]). K=256 via two manually-unrolled
// staged k-halves. Block: 128 rows x 128 cols, 4 waves; wave = 2x8 tiles.
// LDS: stage 69.6 KB (2 blocks/CU); epilogue re-uses as 128x129 fp32.
// K order is the (f, f+64)-pair permutation -- identical on Y and wTb,
// so the contraction is unchanged.
// ---------------------------------------------------------------------------
__global__ __launch_bounds__(256) void mfma_gemm_kernel(const u32* __restrict__ Y,
                                                        const u32* __restrict__ wTb,
                                                        const float* __restrict__ bias,
                                                        float* __restrict__ out) {
    __shared__ alignas(16) unsigned short stage[2][GEMM_ROWS][LDK];  // 69,632 B
    float (*epi)[129] = (float (*)[129])(void*)stage;                // 66,048 B

    const int row0 = blockIdx.x * GEMM_ROWS;
    const int t = threadIdx.x;
    const int lane = t & 63;
    const int wv = t >> 6;

    const int q = lane >> 4;       // quad: k sub-block
    const int ml = lane & 15;      // row within m-tile / col within n-tile
    const int m0 = wv * 32;

    f32x4 acc[2][8];
    #pragma unroll
    for (int mt = 0; mt < 2; mt++)
        #pragma unroll
        for (int nt = 0; nt < 8; nt++) acc[mt][nt] = (f32x4){0.f, 0.f, 0.f, 0.f};

    const int r = t >> 1;
    const int half = t & 1;               // k-quarter within the k-half
    const int gr = row0 + r;

    // ---- k-half 0 ----
    {
        u32* dst = (u32*)&stage[0][r][half * 64];
        if (gr < N_NODES) {
            const u32* p = Y + (size_t)gr * 128 + half * 32;
            #pragma unroll
            for (int j = 0; j < 8; j++)
                *(u32x4*)(dst + j * 4) = *(const u32x4*)(p + j * 4);
        } else {
            #pragma unroll
            for (int j = 0; j < 8; j++)
                *(u32x4*)(dst + j * 4) = (u32x4){0, 0, 0, 0};
        }
        const u32* wp = wTb + (size_t)r * 128 + half * 32;
        u32* wdst = (u32*)&stage[1][r][half * 64];
        #pragma unroll
        for (int j = 0; j < 8; j++)
            *(u32x4*)(wdst + j * 4) = *(const u32x4*)(wp + j * 4);
    }
    __syncthreads();
    #pragma unroll
    for (int kt = 0; kt < 4; kt++) {
        const int k0 = kt * 32 + q * 8;
        const bf16x8 a0 = *(const bf16x8*)&stage[0][m0 + ml][k0];
        const bf16x8 a1 = *(const bf16x8*)&stage[0][m0 + 16 + ml][k0];
        #pragma unroll
        for (int nt = 0; nt < 8; nt++) {
            const bf16x8 b = *(const bf16x8*)&stage[1][nt * 16 + ml][k0];
            acc[0][nt] = __builtin_amdgcn_mfma_f32_16x16x32_bf16(a0, b, acc[0][nt], 0, 0, 0);
            acc[1][nt] = __builtin_amdgcn_mfma_f32_16x16x32_bf16(a1, b, acc[1][nt], 0, 0, 0);
        }
    }
    __syncthreads();

    // ---- k-half 1 ----
    {
        u32* dst = (u32*)&stage[0][r][half * 64];
        if (gr < N_NODES) {
            const u32* p = Y + (size_t)gr * 128 + 64 + half * 32;
            #pragma unroll
            for (int j = 0; j < 8; j++)
                *(u32x4*)(dst + j * 4) = *(const u32x4*)(p + j * 4);
        } else {
            #pragma unroll
            for (int j = 0; j < 8; j++)
                *(u32x4*)(dst + j * 4) = (u32x4){0, 0, 0, 0};
        }
        const u32* wp = wTb + (size_t)r * 128 + 64 + half * 32;
        u32* wdst = (u32*)&stage[1][r][half * 64];
        #pragma unroll
        for (int j = 0; j < 8; j++)
            *(u32x4*)(wdst + j * 4) = *(const u32x4*)(wp + j * 4);
    }
    __syncthreads();
    #pragma unroll
    for (int kt = 0; kt < 4; kt++) {
        const int k0 = kt * 32 + q * 8;
        const bf16x8 a0 = *(const bf16x8*)&stage[0][m0 + ml][k0];
        const bf16x8 a1 = *(const bf16x8*)&stage[0][m0 + 16 + ml][k0];
        #pragma unroll
        for (int nt = 0; nt < 8; nt++) {
            const bf16x8 b = *(const bf16x8*)&stage[1][nt * 16 + ml][k0];
            acc[0][nt] = __builtin_amdgcn_mfma_f32_16x16x32_bf16(a0, b, acc[0][nt], 0, 0, 0);
            acc[1][nt] = __builtin_amdgcn_mfma_f32_16x16x32_bf16(a1, b, acc[1][nt], 0, 0, 0);
        }
    }
    __syncthreads();   // done reading stage; epi aliases it

    // C-layout (col=lane&15, row=quad*4+reg) -> LDS fp32 [row][feat]
    #pragma unroll
    for (int mt = 0; mt < 2; mt++)
        #pragma unroll
        for (int nt = 0; nt < 8; nt++)
            #pragma unroll
            for (int rr = 0; rr < 4; rr++)
                epi[m0 + mt * 16 + q * 4 + rr][nt * 16 + ml] = acc[mt][nt][rr];
    __syncthreads();

    // fused bias + relu, coalesced fp32 store
    if (gr < N_NODES) {
        float* op = out + (size_t)gr * DOUT + half * 64;
        const float* bp = bias + half * 64;
        #pragma unroll
        for (int j = 0; j < 16; j++) {
            const f32x4 bv = *(const f32x4*)(bp + j * 4);
            f32x4 v = *(const f32x4*)&epi[r][half * 64 + j * 4];
            v.x = fmaxf(v.x + bv.x, 0.f);
            v.y = fmaxf(v.y + bv.y, 0.f);
            v.z = fmaxf(v.z + bv.z, 0.f);
            v.w = fmaxf(v.w + bv.w, 0.f);
            __builtin_nontemporal_store(v, (f32x4*)(op + j * 4));
        }
    }
}

extern "C" void kernel_launch(void* const* d_in, const int* in_sizes, int n_in,
                              void* d_out, int out_size, void* d_ws, size_t ws_size,
                              hipStream_t stream) {
    (void)in_sizes; (void)n_in; (void)out_size; (void)ws_size;
    const float* x        = (const float*)d_in[0];   // [N, 128]
    const float* w        = (const float*)d_in[1];   // [2, 128, 128]
    const float* bias     = (const float*)d_in[2];   // [128]
    const float* sup_vals = (const float*)d_in[3];   // [2, E] flat
    const int*   sup_rows = (const int*)d_in[4];     // [2, E] flat
    const int*   sup_cols = (const int*)d_in[5];     // [2, E] flat
    float* out = (float*)d_out;                      // [N, 128]

    // ws layout: xb | edata | Y | bins | wTb  (~102.5 MB; edata and Y are
    // simultaneously live in bingather -> no aliasing)
    char* ws = (char*)d_ws;
    u32*   xb     = (u32*)ws;                                   // 25.6 MB
    u32x2* edata  = (u32x2*)(ws + (size_t)N_NODES * 64 * 4);    // 25.6 MB
    u32*   Y      = (u32*)((char*)edata + (size_t)E_TOT * 8);   // 51.2 MB
    int*   bin_cnt   = (int*)((char*)Y + (size_t)N_NODES * 128 * 4);
    int*   bin_base  = bin_cnt + NBINS;              // NBINS+1
    int*   bin_cursor= bin_base + NBINS + 1;
    u32*   wTb       = (u32*)(bin_cursor + NBINS);   // 64 KB

    // 1. convert x -> bf16 table, w -> stacked transposed bf16
    xconv_kernel<<<(N_NODES * 16 + 255) / 256, 256, 0, stream>>>(x, xb);
    wconv_kernel<<<N_SUP, 256, 0, stream>>>(w, wTb);
    // 2. bin CSR build (both supports merged; no row sort needed)
    (void)hipMemsetAsync(bin_cnt, 0, NBINS * sizeof(int), stream);
    binhist_kernel<<<NBLK_SC, 256, 0, stream>>>(sup_rows, bin_cnt);
    binscan_kernel<<<1, 1024, 0, stream>>>(bin_cnt, bin_base, bin_cursor);
    binscatter_kernel<<<NBLK_SC, 256, 0, stream>>>(sup_rows, sup_cols, sup_vals,
                                                   bin_cursor, edata);
    // 3. bin gather with LDS fp32 accumulation -> Y (replaces binsort+gather)
    bingather_kernel<<<NBINS, 1024, 0, stream>>>(xb, edata, bin_base, Y);
    // 4. K=256 MFMA GEMM with fused bias + ReLU
    mfma_gemm_kernel<<<(N_NODES + GEMM_ROWS - 1) / GEMM_ROWS, 256, 0, stream>>>(Y, wTb, bias, out);
}

// Round 7
// 432.330 us; speedup vs baseline: 6.9247x; 6.9192x over previous
//
#include <hip/hip_runtime.h>

#define N_NODES 100000
#define N_EDGES 1600000
#define DIN 128
#define DOUT 128
#define N_SUP 2
#define E_TOT (N_SUP * N_EDGES)          // 3,200,000

#define BIN_ROWS 128
#define BSHIFT 7
#define NBINS ((N_NODES + BIN_ROWS - 1) / BIN_ROWS)    // 782

#define SC_EPT 16
#define SC_BLOCK 256
#define SC_CHUNK (SC_EPT * SC_BLOCK)                    // 4096
#define NBLK_SC ((E_TOT + SC_CHUNK - 1) / SC_CHUNK)     // 782

#define GEMM_ROWS 128
#define LDK 136      // padded LDS k-stride in bf16 units (odd multiple of 8)

typedef float        f32x2 __attribute__((ext_vector_type(2)));
typedef float        f32x4 __attribute__((ext_vector_type(4)));
typedef unsigned int u32;
typedef u32          u32x2 __attribute__((ext_vector_type(2)));
typedef u32          u32x4 __attribute__((ext_vector_type(4)));
typedef short        bf16x8 __attribute__((ext_vector_type(8)));

// round-to-nearest-even fp32 -> bf16 pair packed in one u32 (lo = even idx)
static __device__ __forceinline__ u32 pack_bf16x2(float lo, float hi) {
    u32 ul = __float_as_uint(lo);
    u32 uh = __float_as_uint(hi);
    ul = (ul + 0x7FFFu + ((ul >> 16) & 1u)) >> 16;
    uh = ((uh + 0x7FFFu + ((uh >> 16) & 1u)) >> 16) << 16;
    return ul | uh;
}

// ---------------------------------------------------------------------------
// w[s][k][n] fp32 -> wT[s][n][k] packed bf16 (k-pairs in u32, lo = even k)
// ---------------------------------------------------------------------------
__global__ __launch_bounds__(256) void wconv_kernel(const float* __restrict__ w,
                                                    u32* __restrict__ wTb) {
    const int s = blockIdx.x;
    const int n = threadIdx.x >> 1;
    const int kh = (threadIdx.x & 1) * 64;
    const float* wp = w + (size_t)s * DIN * DOUT + n;
    u32 o[32];
    #pragma unroll
    for (int j = 0; j < 32; j++) {
        const float lo = wp[(size_t)(kh + 2 * j) * DOUT];
        const float hi = wp[(size_t)(kh + 2 * j + 1) * DOUT];
        o[j] = pack_bf16x2(lo, hi);
    }
    u32* op = wTb + ((size_t)s * 128 + n) * 64 + kh / 2;
    #pragma unroll
    for (int j = 0; j < 8; j++)
        *(u32x4*)(op + j * 4) = *(u32x4*)&o[j * 4];
}

// ---------------------------------------------------------------------------
// MFMA GEMM: pre[s] = x @ w[s] in bf16 (16x16x32 MFMA, fp32 accumulate).
// x is read DIRECTLY as fp32 and converted to bf16 during LDS staging
// (xconv kernel folded in: deletes one kernel + 26 MB of traffic).
// Block: 128 rows x 128 cols, 4 waves; wave = 2 m-tiles x 8 n-tiles.
// LDS: xs[128][LDK] + ws[128][LDK] bf16 (69.6 KB, 2 blocks/CU); epilogue
// re-uses the same LDS as a 128x129 fp32 transpose buffer.
// ---------------------------------------------------------------------------
__global__ __launch_bounds__(256) void mfma_gemm_kernel(const float* __restrict__ x,
                                                        const u32* __restrict__ wTb,
                                                        u32* __restrict__ pre) {
    __shared__ alignas(16) unsigned short stage[2][GEMM_ROWS][LDK];  // 69,632 B
    float (*epi)[129] = (float (*)[129])(void*)stage;                // 66,048 B

    const int s = blockIdx.y;
    const int row0 = blockIdx.x * GEMM_ROWS;
    const int t = threadIdx.x;
    const int lane = t & 63;
    const int wv = t >> 6;

    // stage x tile (rows row0..row0+127): fp32 -> packed bf16 LDS rows
    {
        const int r = t >> 1;
        const int half = t & 1;               // k 0..63 / 64..127
        const int gr = row0 + r;
        u32* dst = (u32*)&stage[0][r][half * 64];
        u32 o[32];
        if (gr < N_NODES) {
            const float* p = x + (size_t)gr * DIN + half * 64;
            #pragma unroll
            for (int j = 0; j < 16; j++) {
                const f32x4 a = *(const f32x4*)(p + j * 4);
                o[2 * j]     = pack_bf16x2(a.x, a.y);
                o[2 * j + 1] = pack_bf16x2(a.z, a.w);
            }
        } else {
            #pragma unroll
            for (int j = 0; j < 32; j++) o[j] = 0;
        }
        #pragma unroll
        for (int j = 0; j < 8; j++)
            *(u32x4*)(dst + j * 4) = *(u32x4*)&o[j * 4];
        // stage wT[s] (128 n-rows x 128 k)
        const u32* wp = wTb + ((size_t)s * 128 + r) * 64 + half * 32;
        u32* wdst = (u32*)&stage[1][r][half * 64];
        #pragma unroll
        for (int j = 0; j < 8; j++)
            *(u32x4*)(wdst + j * 4) = *(const u32x4*)(wp + j * 4);
    }
    __syncthreads();

    const int q = lane >> 4;       // quad: k sub-block
    const int ml = lane & 15;      // row within m-tile / col within n-tile
    const int m0 = wv * 32;

    f32x4 acc[2][8];
    #pragma unroll
    for (int mt = 0; mt < 2; mt++)
        #pragma unroll
        for (int nt = 0; nt < 8; nt++) acc[mt][nt] = (f32x4){0.f, 0.f, 0.f, 0.f};

    #pragma unroll
    for (int kt = 0; kt < 4; kt++) {
        const int k0 = kt * 32 + q * 8;
        const bf16x8 a0 = *(const bf16x8*)&stage[0][m0 + ml][k0];
        const bf16x8 a1 = *(const bf16x8*)&stage[0][m0 + 16 + ml][k0];
        #pragma unroll
        for (int nt = 0; nt < 8; nt++) {
            const bf16x8 b = *(const bf16x8*)&stage[1][nt * 16 + ml][k0];
            acc[0][nt] = __builtin_amdgcn_mfma_f32_16x16x32_bf16(a0, b, acc[0][nt], 0, 0, 0);
            acc[1][nt] = __builtin_amdgcn_mfma_f32_16x16x32_bf16(a1, b, acc[1][nt], 0, 0, 0);
        }
    }
    __syncthreads();   // done reading stage; epi aliases it

    // C-layout (col=lane&15, row=quad*4+reg) -> LDS fp32 [row][feat]
    #pragma unroll
    for (int mt = 0; mt < 2; mt++)
        #pragma unroll
        for (int nt = 0; nt < 8; nt++)
            #pragma unroll
            for (int r = 0; r < 4; r++)
                epi[m0 + mt * 16 + q * 4 + r][nt * 16 + ml] = acc[mt][nt][r];
    __syncthreads();

    // packed bf16-pair store, coalesced
    {
        const int row = t >> 1;
        const int half = t & 1;
        const int gr = row0 + row;
        if (gr < N_NODES) {
            u32 ov[32];
            #pragma unroll
            for (int j = 0; j < 32; j++)
                ov[j] = pack_bf16x2(epi[row][half * 64 + 2 * j],
                                    epi[row][half * 64 + 2 * j + 1]);
            u32* op = pre + ((size_t)s * N_NODES + gr) * 64 + half * 32;
            #pragma unroll
            for (int j = 0; j < 8; j++)
                __builtin_nontemporal_store(*(u32x4*)&ov[j * 4], (u32x4*)(op + j * 4));
        }
    }
}

// ---------------------------------------------------------------------------
// Bin histogram: LDS hist per block, one global atomic per (block, bin)
// ---------------------------------------------------------------------------
__global__ __launch_bounds__(256) void binhist_kernel(const int* __restrict__ rows,
                                                      int* __restrict__ bin_cnt) {
    __shared__ int h[NBINS];
    const int t = threadIdx.x;
    for (int i = t; i < NBINS; i += 256) h[i] = 0;
    __syncthreads();
    const int base = blockIdx.x * SC_CHUNK;
    #pragma unroll
    for (int j = 0; j < SC_EPT; j++) {
        const int i = base + j * 256 + t;
        if (i < E_TOT) atomicAdd(&h[__builtin_nontemporal_load(rows + i) >> BSHIFT], 1);
    }
    __syncthreads();
    for (int i = t; i < NBINS; i += 256)
        if (h[i]) atomicAdd(&bin_cnt[i], h[i]);
}

// ---------------------------------------------------------------------------
// Exclusive scan over NBINS (single block)
// ---------------------------------------------------------------------------
__global__ __launch_bounds__(1024) void binscan_kernel(const int* __restrict__ bin_cnt,
                                                       int* __restrict__ bin_base,
                                                       int* __restrict__ bin_cursor) {
    __shared__ int s[1024];
    const int t = threadIdx.x;
    const int v = (t < NBINS) ? bin_cnt[t] : 0;
    s[t] = v;
    __syncthreads();
    #pragma unroll
    for (int off = 1; off < 1024; off <<= 1) {
        const int u = (t >= off) ? s[t - off] : 0;
        __syncthreads();
        s[t] += u;
        __syncthreads();
    }
    if (t < NBINS) {
        const int ex = s[t] - v;
        bin_base[t] = ex;
        bin_cursor[t] = ex;
    }
    if (t == 0) bin_base[NBINS] = E_TOT;
}

// ---------------------------------------------------------------------------
// Binned scatter: per-block LDS bin counts, one global run reservation per
// (block,bin), stores at run_base + local_pos (block-local contiguous runs).
// payload.x = col_eff (18b) | row_low (7b) << 18 ; payload.y = val bits
// ---------------------------------------------------------------------------
__global__ __launch_bounds__(256) void binscatter_kernel(const int* __restrict__ rows,
                                                         const int* __restrict__ cols,
                                                         const float* __restrict__ vals,
                                                         int* __restrict__ bin_cursor,
                                                         u32x2* __restrict__ edata) {
    __shared__ int lcnt[NBINS];
    __shared__ int lbase[NBINS];
    const int t = threadIdx.x;
    for (int i = t; i < NBINS; i += 256) lcnt[i] = 0;
    __syncthreads();

    const int base = blockIdx.x * SC_CHUNK;
    int bin[SC_EPT], lpos[SC_EPT];
    u32x2 pay[SC_EPT];
    #pragma unroll
    for (int j = 0; j < SC_EPT; j++) {
        const int i = base + j * 256 + t;
        if (i < E_TOT) {
            const int r = __builtin_nontemporal_load(rows + i);
            const int c = __builtin_nontemporal_load(cols + i);
            const float v = __builtin_nontemporal_load(vals + i);
            const int b = r >> BSHIFT;
            bin[j] = b;
            lpos[j] = atomicAdd(&lcnt[b], 1);
            pay[j].x = (u32)(c + ((i >= N_EDGES) ? N_NODES : 0)) |
                       ((u32)(r & (BIN_ROWS - 1)) << 18);
            pay[j].y = __float_as_uint(v);
        } else {
            bin[j] = -1;
        }
    }
    __syncthreads();
    for (int b = t; b < NBINS; b += 256) {
        const int c = lcnt[b];
        if (c) lbase[b] = atomicAdd(&bin_cursor[b], c);
    }
    __syncthreads();
    #pragma unroll
    for (int j = 0; j < SC_EPT; j++) {
        if (bin[j] >= 0) edata[lbase[bin[j]] + lpos[j]] = pay[j];
    }
}

// ---------------------------------------------------------------------------
// Bin sort: one block per bin; row-sorts the bin's edges into edata2 and
// emits per-row CSR offsets. All traffic stays in a ~32 KB L2-local window.
// ---------------------------------------------------------------------------
__global__ __launch_bounds__(256) void binsort_kernel(const u32x2* __restrict__ edata,
                                                      u32x2* __restrict__ edata2,
                                                      const int* __restrict__ bin_base,
                                                      int* __restrict__ row_start) {
    __shared__ int rcnt[BIN_ROWS];
    __shared__ int rscan[BIN_ROWS];
    const int t = threadIdx.x;
    const int b = blockIdx.x;
    const int beg = bin_base[b];
    const int end = bin_base[b + 1];

    if (t < BIN_ROWS) rcnt[t] = 0;
    __syncthreads();
    for (int e = beg + t; e < end; e += 256)
        atomicAdd(&rcnt[edata[e].x >> 18], 1);
    __syncthreads();

    const int v = (t < BIN_ROWS) ? rcnt[t] : 0;
    if (t < BIN_ROWS) rscan[t] = v;
    __syncthreads();
    #pragma unroll
    for (int off = 1; off < BIN_ROWS; off <<= 1) {
        const int u = (t < BIN_ROWS && t >= off) ? rscan[t - off] : 0;
        __syncthreads();
        if (t < BIN_ROWS) rscan[t] += u;
        __syncthreads();
    }
    if (t < BIN_ROWS) {
        const int ex = rscan[t] - v;
        rcnt[t] = ex;                       // reuse as cursor
        const int row = b * BIN_ROWS + t;
        if (row < N_NODES) row_start[row] = beg + ex;
    }
    __syncthreads();
    for (int e = beg + t; e < end; e += 256) {
        const u32x2 d = edata[e];
        const int pos = beg + atomicAdd(&rcnt[d.x >> 18], 1);
        u32x2 o;
        o.x = d.x & 0x3FFFFu;
        o.y = d.y;
        edata2[pos] = o;
    }
    if (b == NBINS - 1 && t == 0) row_start[N_NODES] = E_TOT;
}

// ---------------------------------------------------------------------------
// Gather-accumulate (no atomics): one wave per row, lane l owns features
// 2l, 2l+1 (one packed bf16x2 u32 per edge). Fused bias + ReLU.
// Two-stage software pipeline: while batch i's eight 256B gathers are in
// flight, batch i+1's edata descriptors are loaded (compiler emits the
// counted vmcnt(8) wait) -- removes descriptor latency from the loop-
// carried critical path. u32 pre offsets (SGPR base + voffset).
// __launch_bounds__(256,6): ~24 waves/CU (matches measured occupancy),
// VGPR budget ~84 >> the ~50 needed (d+dn+u).
// ---------------------------------------------------------------------------
__global__ __launch_bounds__(256, 6) void gather_kernel(const u32* __restrict__ pre,
                                                        const u32x2* __restrict__ edata2,
                                                        const int* __restrict__ row_start,
                                                        const float* __restrict__ bias,
                                                        float* __restrict__ out) {
    const int lane = threadIdx.x & 63;
    const int wid = threadIdx.x >> 6;
    const int row = blockIdx.x * 4 + wid;
    if (row >= N_NODES) return;

    const int beg = row_start[row];
    const int end = row_start[row + 1];

    float ax = 0.f, ay = 0.f;
    int e = beg;

    if (e + 8 <= end) {
        u32x2 d[8];
        #pragma unroll
        for (int j = 0; j < 8; j++)
            d[j] = __builtin_nontemporal_load(edata2 + e + j);
        for (;;) {
            u32 u[8];
            #pragma unroll
            for (int j = 0; j < 8; j++)
                u[j] = pre[(u32)((d[j].x << 6) + (u32)lane)];
            const int en = e + 8;
            const bool more = (en + 8 <= end);   // wave-uniform
            u32x2 dn[8];
            if (more) {
                #pragma unroll
                for (int j = 0; j < 8; j++)
                    dn[j] = __builtin_nontemporal_load(edata2 + en + j);
            }
            #pragma unroll
            for (int j = 0; j < 8; j++) {
                const float v = __uint_as_float(d[j].y);
                ax = fmaf(v, __uint_as_float(u[j] << 16), ax);
                ay = fmaf(v, __uint_as_float(u[j] & 0xFFFF0000u), ay);
            }
            e = en;
            if (!more) break;
            #pragma unroll
            for (int j = 0; j < 8; j++) d[j] = dn[j];
        }
    }
    // mid: 4 edges per batch
    for (; e + 4 <= end; e += 4) {
        u32x2 d[4];
        #pragma unroll
        for (int j = 0; j < 4; j++)
            d[j] = __builtin_nontemporal_load(edata2 + e + j);
        u32 u[4];
        #pragma unroll
        for (int j = 0; j < 4; j++)
            u[j] = pre[(u32)((d[j].x << 6) + (u32)lane)];
        #pragma unroll
        for (int j = 0; j < 4; j++) {
            const float v = __uint_as_float(d[j].y);
            ax = fmaf(v, __uint_as_float(u[j] << 16), ax);
            ay = fmaf(v, __uint_as_float(u[j] & 0xFFFF0000u), ay);
        }
    }
    // tail
    for (; e < end; e++) {
        const u32x2 d = __builtin_nontemporal_load(edata2 + e);
        const u32 u = pre[(u32)((d.x << 6) + (u32)lane)];
        const float v = __uint_as_float(d.y);
        ax = fmaf(v, __uint_as_float(u << 16), ax);
        ay = fmaf(v, __uint_as_float(u & 0xFFFF0000u), ay);
    }

    const float2 b = *(const float2*)(bias + lane * 2);
    f32x2 r;
    r.x = fmaxf(ax + b.x, 0.f);
    r.y = fmaxf(ay + b.y, 0.f);
    __builtin_nontemporal_store(r, (f32x2*)(out + (size_t)row * DOUT + lane * 2));
}

extern "C" void kernel_launch(void* const* d_in, const int* in_sizes, int n_in,
                              void* d_out, int out_size, void* d_ws, size_t ws_size,
                              hipStream_t stream) {
    (void)in_sizes; (void)n_in; (void)out_size; (void)ws_size;
    const float* x        = (const float*)d_in[0];   // [N, 128]
    const float* w        = (const float*)d_in[1];   // [2, 128, 128]
    const float* bias     = (const float*)d_in[2];   // [128]
    const float* sup_vals = (const float*)d_in[3];   // [2, E] flat
    const int*   sup_rows = (const int*)d_in[4];     // [2, E] flat
    const int*   sup_cols = (const int*)d_in[5];     // [2, E] flat
    float* out = (float*)d_out;                      // [N, 128]

    // ws layout: pre | edata | edata2 | bins | row_start | wTb  (~102.5 MB)
    char* ws = (char*)d_ws;
    u32*   pre       = (u32*)ws;                                        // 51.2 MB
    u32x2* edata     = (u32x2*)(ws + (size_t)N_SUP * N_NODES * 64 * 4); // 25.6 MB
    u32x2* edata2    = (u32x2*)((char*)edata + (size_t)E_TOT * 8);      // 25.6 MB
    int*   bin_cnt   = (int*)((char*)edata2 + (size_t)E_TOT * 8);
    int*   bin_base  = bin_cnt + NBINS;              // NBINS+1
    int*   bin_cursor= bin_base + NBINS + 1;
    int*   row_start = bin_cursor + NBINS;           // N+1
    u32*   wTb       = (u32*)(row_start + N_NODES + 1);   // 64 KB

    // 1. convert w -> transposed bf16 (x conversion folded into GEMM)
    wconv_kernel<<<N_SUP, 256, 0, stream>>>(w, wTb);
    // 2. MFMA GEMM -> bf16 pre (reads x fp32 directly)
    {
        dim3 grid((N_NODES + GEMM_ROWS - 1) / GEMM_ROWS, N_SUP);
        mfma_gemm_kernel<<<grid, 256, 0, stream>>>(x, wTb, pre);
    }
    // 3. bin CSR build + per-bin row sort
    (void)hipMemsetAsync(bin_cnt, 0, NBINS * sizeof(int), stream);
    binhist_kernel<<<NBLK_SC, 256, 0, stream>>>(sup_rows, bin_cnt);
    binscan_kernel<<<1, 1024, 0, stream>>>(bin_cnt, bin_base, bin_cursor);
    binscatter_kernel<<<NBLK_SC, 256, 0, stream>>>(sup_rows, sup_cols, sup_vals,
                                                   bin_cursor, edata);
    binsort_kernel<<<NBINS, 256, 0, stream>>>(edata, edata2, bin_base, row_start);
    // 4. row gather + bias + ReLU (no atomics)
    gather_kernel<<<(N_NODES + 3) / 4, 256, 0, stream>>>(pre, edata2, row_start, bias, out);
}